// Round 1
// baseline (454.810 us; speedup 1.0000x reference)
//
#include <hip/hip_runtime.h>
#include <stdint.h>
#include <math.h>

// Problem constants (reference file)
#define NROW 8192   // N rows of input
#define KDIM 2048   // F_IN
#define NDIM 2048   // F_OUT
//
// Reference reduces EXACTLY to out = elu(input @ W):
//   scores = where(eye>0, e, -9e15)  -> softmax rows are one-hot (exp(-9e15) == 0 in fp32)
//   attention = I  ->  h_prime = h.
// adj and a are numerically unused.

typedef __attribute__((ext_vector_type(8))) short bf16x8;  // 8 bf16 = 4 VGPRs
typedef __attribute__((ext_vector_type(4))) float f32x4;

__device__ __forceinline__ unsigned short f32_to_bf16(float f) {
    union { float f; unsigned int u; } v; v.f = f;
    unsigned int u = v.u;
    unsigned int r = u + 0x7FFFu + ((u >> 16) & 1u);  // RNE
    return (unsigned short)(r >> 16);
}

// input (fp32, row-major) -> bf16, elementwise, float4/ushort4 vectorized
__global__ void cvt_bf16_kernel(const float* __restrict__ in,
                                unsigned short* __restrict__ out) {
    int i = (blockIdx.x * 256 + threadIdx.x) * 4;
    float4 f = *(const float4*)(in + i);
    ushort4 o;
    o.x = f32_to_bf16(f.x);
    o.y = f32_to_bf16(f.y);
    o.z = f32_to_bf16(f.z);
    o.w = f32_to_bf16(f.w);
    *(ushort4*)(out + i) = o;
}

// W (K x N fp32 row-major) -> Wt (N x K bf16): B^T form so GEMM reads contiguous k
__global__ void cvt_transpose_kernel(const float* __restrict__ W,
                                     unsigned short* __restrict__ Wt) {
    __shared__ float tile[32][33];  // +1 pad: no bank conflicts
    int tx = threadIdx.x, ty = threadIdx.y;   // (32, 8)
    int x0 = blockIdx.x * 32, y0 = blockIdx.y * 32;
    #pragma unroll
    for (int j = 0; j < 32; j += 8)
        tile[ty + j][tx] = W[(size_t)(y0 + ty + j) * NDIM + x0 + tx];
    __syncthreads();
    #pragma unroll
    for (int j = 0; j < 32; j += 8)
        Wt[(size_t)(x0 + ty + j) * KDIM + y0 + tx] = f32_to_bf16(tile[tx][ty + j]);
}

// ---------------- GEMM: C[M,N] = elu(A[M,K] * Wt[N,K]^T), m97-style ----------------
#define BM 128
#define BN 128
#define BK 32

__device__ __forceinline__ void async_ld16(const unsigned short* g, unsigned short* l) {
    __builtin_amdgcn_global_load_lds(
        (const __attribute__((address_space(1))) void*)g,
        (__attribute__((address_space(3))) void*)l,
        16, 0, 0);
}

__global__ __launch_bounds__(256)
void gemm_bf16_elu(const unsigned short* __restrict__ A,   // M x K bf16
                   const unsigned short* __restrict__ Bt,  // N x K bf16 (= W^T)
                   float* __restrict__ C) {                // M x N fp32
    __shared__ unsigned short As[BM * BK];  // [m][k] contiguous (global_load_lds order)
    __shared__ unsigned short Bs[BN * BK];  // [n][k] contiguous

    const int tid  = threadIdx.x;
    const int wave = tid >> 6;
    const int lane = tid & 63;
    const int quad = lane >> 4;
    const int lo   = lane & 15;

    const int m0 = blockIdx.y * BM;
    const int n0 = blockIdx.x * BN;
    const int wm = (wave >> 1) * 64;   // wave's 64x64 subtile
    const int wn = (wave & 1) * 64;

    // Staging: chunk g in [0,512): tile-row g>>2, 8-elem quarter g&3; LDS byte off g*16.
    // Wave-contiguous lane order matches global_load_lds's uniform-base+lane*16 rule.
    const int g0 = tid, g1 = tid + 256;
    const unsigned short* gA0 = A  + (size_t)(m0 + (g0 >> 2)) * KDIM + (g0 & 3) * 8;
    const unsigned short* gA1 = A  + (size_t)(m0 + (g1 >> 2)) * KDIM + (g1 & 3) * 8;
    const unsigned short* gB0 = Bt + (size_t)(n0 + (g0 >> 2)) * KDIM + (g0 & 3) * 8;
    const unsigned short* gB1 = Bt + (size_t)(n0 + (g1 >> 2)) * KDIM + (g1 & 3) * 8;
    unsigned short* lA0 = As + g0 * 8;
    unsigned short* lA1 = As + g1 * 8;
    unsigned short* lB0 = Bs + g0 * 8;
    unsigned short* lB1 = Bs + g1 * 8;

    f32x4 acc[4][4];
    #pragma unroll
    for (int i = 0; i < 4; ++i)
        #pragma unroll
        for (int j = 0; j < 4; ++j) {
            f32x4 z = {0.f, 0.f, 0.f, 0.f};
            acc[i][j] = z;
        }

    for (int k0 = 0; k0 < KDIM; k0 += BK) {
        async_ld16(gA0 + k0, lA0);
        async_ld16(gA1 + k0, lA1);
        async_ld16(gB0 + k0, lB0);
        async_ld16(gB1 + k0, lB1);
        __syncthreads();  // compiler drains vmcnt before s_barrier -> LDS valid for all waves

        // A frag: [m=lane&15][k=quad*8+j] ; B frag: [n=lane&15][k=quad*8+j]
        bf16x8 af[4], bg[4];
        #pragma unroll
        for (int i = 0; i < 4; ++i)
            af[i] = *(const bf16x8*)(As + (wm + i * 16 + lo) * BK + quad * 8);
        #pragma unroll
        for (int j = 0; j < 4; ++j)
            bg[j] = *(const bf16x8*)(Bs + (wn + j * 16 + lo) * BK + quad * 8);

        #pragma unroll
        for (int i = 0; i < 4; ++i)
            #pragma unroll
            for (int j = 0; j < 4; ++j)
                acc[i][j] = __builtin_amdgcn_mfma_f32_16x16x32_bf16(
                    af[i], bg[j], acc[i][j], 0, 0, 0);

        __syncthreads();  // all waves done reading LDS before next iter's loads land
    }

    // Epilogue: C/D layout col=lane&15, row=quad*4+reg. Fused elu, fp32 store.
    #pragma unroll
    for (int i = 0; i < 4; ++i) {
        #pragma unroll
        for (int r = 0; r < 4; ++r) {
            int m = m0 + wm + i * 16 + quad * 4 + r;
            float* crow = C + (size_t)m * NDIM + n0 + wn + lo;
            #pragma unroll
            for (int j = 0; j < 4; ++j) {
                float v = acc[i][j][r];
                crow[j * 16] = (v > 0.f) ? v : (__expf(v) - 1.f);
            }
        }
    }
}

extern "C" void kernel_launch(void* const* d_in, const int* in_sizes, int n_in,
                              void* d_out, int out_size, void* d_ws, size_t ws_size,
                              hipStream_t stream) {
    const float* input = (const float*)d_in[0];
    // d_in[1] = adj  : numerically unused (attention == I exactly)
    const float* W     = (const float*)d_in[2];
    // d_in[3] = a    : numerically unused
    float* out = (float*)d_out;

    // Workspace: A_bf16 (M*K*2 = 33.5 MB) then Wt_bf16 (N*K*2 = 8.4 MB) = 42 MB total
    unsigned short* Abf = (unsigned short*)d_ws;
    unsigned short* Wt  = Abf + (size_t)NROW * KDIM;

    // 1) input fp32 -> bf16 (16384 blocks x 256 thr, 4 elems each: exact cover)
    cvt_bf16_kernel<<<(NROW * KDIM) / 4 / 256, 256, 0, stream>>>(input, Abf);

    // 2) W fp32 -> Wt bf16 transposed
    cvt_transpose_kernel<<<dim3(NDIM / 32, KDIM / 32), dim3(32, 8), 0, stream>>>(W, Wt);

    // 3) GEMM + elu
    gemm_bf16_elu<<<dim3(NDIM / BN, NROW / BM), 256, 0, stream>>>(Abf, Wt, out);
}